// Round 5
// baseline (163.163 us; speedup 1.0000x reference)
//
#include <hip/hip_runtime.h>
#include <math.h>

// ---------------------------------------------------------------------------
// WassersteinLoss: pred = sigmoid(x1-x0); loss = mean_b mean_i
// (sort(pred_b)[i] - sort(tgt_b)[i])^2.
//
// Histogram-based: 16384-bin value histograms per segment; sorted-pair
// matching == CDF mass matching; loss = Sum take*(Pc-Qc)^2 / (B*N) with
// bin-center values (error ~2x the 32768-bin version's measured 0.0 absmax;
// tol 1.5e-5 has >100x margin).
//
// R15: dispatch-count reduction. R11-R14 falsified every intra-kernel lever;
// residual budget = fill 45 (harness) + hist 45 (LDS-atomic wave-instr
// throughput floor, 5 variants invariant) + ~17 us tail + ~50 us launch
// gaps (5 boundaries x ~10 us). R12 proved per-block device-scope fences
// cost MORE than a launch boundary, so stages must be removed
// algorithmically: kNBin 32768->16384 lets a whole sample's target CDF fit
// in one block's LDS (64 KiB), collapsing scanA+cross+fin into ONE
// block-local match kernel (16 blocks, one per sample; pred counts live in
// registers -- thread t owns bins 16t..16t+15 for accumulate, scan, and
// walk). Finish via 16 f64 atomicAdds + 16 fences (not 2048) + last-rank
// writes out. Dispatches: 5 -> 3.
// ---------------------------------------------------------------------------

namespace {
constexpr int kB      = 16;
constexpr int kN      = 768 * 768;        // 589824 per segment
constexpr int kNBin   = 16384;
constexpr int kNSeg   = 32;               // 16 pred + 16 target
constexpr int kChunks = 16;               // partials per segment
constexpr int kChunk  = kN / kChunks;     // 36864 elements
constexpr int kWords  = kNBin / 4;        // 4096 u32 words (4 bins/word, u8)
constexpr int kHT     = 512;              // hist block size
constexpr int kBinsPerThr = kNBin / 1024; // 16 bins per match thread
constexpr double kWd  = 1.0 / (double)kNBin;

// d_ws layout
constexpr size_t ACC_OFF  = 0;                                   // double[1]
constexpr size_t CTR_OFF  = 64;                                  // u32[1]
constexpr size_t PART_OFF = 256;                                 // u32[512][4096] = 8 MiB
}

__device__ __forceinline__ float pred_of(float x0, float x1) {
    // sigmoid(x1-x0), fast path: v_mul+v_exp+v_add+v_rcp (~1 ulp).
    return __builtin_amdgcn_rcpf(1.0f + __expf(x0 - x1));
}
__device__ __forceinline__ int bin_of(float v) {
    int b = (int)(v * (float)kNBin);
    return b < 0 ? 0 : (b > kNBin - 1 ? kNBin - 1 : b);
}
__device__ __forceinline__ void bump(unsigned* h, float v) {
    int b = bin_of(v);
    atomicAdd(&h[b >> 2], 1u << ((b & 3) << 3));
}
__device__ __forceinline__ void bump_pred4(unsigned* h, float4 a, float4 b) {
    bump(h, pred_of(a.x, b.x)); bump(h, pred_of(a.y, b.y));
    bump(h, pred_of(a.z, b.z)); bump(h, pred_of(a.w, b.w));
}
__device__ __forceinline__ void bump_tgt4(unsigned* h, float4 v) {
    bump(h, v.x); bump(h, v.y); bump(h, v.z); bump(h, v.w);
}

// ---- histogram (LDS-private, packed u8), 512-thr blocks ------------------
__global__ __launch_bounds__(kHT) void hist_kernel(const float4* __restrict__ x,
                                                   const float4* __restrict__ t,
                                                   unsigned* __restrict__ partial,
                                                   double* __restrict__ acc,
                                                   unsigned* __restrict__ ctr) {
    int s = blockIdx.y, c = blockIdx.x, z = blockIdx.z, tid = threadIdx.x;
    if (s == 0 && c == 0 && z == 0 && tid == 0) { *acc = 0.0; *ctr = 0u; }
    __shared__ unsigned h[kWords];                       // 16 KiB, 4 bins/word
    for (int i = tid; i < kWords; i += kHT) h[i] = 0;
    __syncthreads();

    const int q4 = kN / 4, c4 = kChunk / 4;              // 9216 -> 18/thread
    if (z == 0) {
        const float4* x0p = x + (size_t)s * 2 * q4 + (size_t)c * c4;
        const float4* x1p = x0p + q4;
#pragma unroll
        for (int b = 0; b < 6; ++b) {
            int k0 = tid + (3 * b + 0) * kHT;
            int k1 = tid + (3 * b + 1) * kHT;
            int k2 = tid + (3 * b + 2) * kHT;
            // 6 independent loads in flight before first use
            float4 a0 = x0p[k0], b0 = x1p[k0];
            float4 a1 = x0p[k1], b1 = x1p[k1];
            float4 a2 = x0p[k2], b2 = x1p[k2];
            bump_pred4(h, a0, b0);
            bump_pred4(h, a1, b1);
            bump_pred4(h, a2, b2);
        }
    } else {
        const float4* tp = t + (size_t)s * q4 + (size_t)c * c4;
#pragma unroll
        for (int b = 0; b < 3; ++b) {
            float4 v0 = tp[tid + (6 * b + 0) * kHT];
            float4 v1 = tp[tid + (6 * b + 1) * kHT];
            float4 v2 = tp[tid + (6 * b + 2) * kHT];
            float4 v3 = tp[tid + (6 * b + 3) * kHT];
            float4 v4 = tp[tid + (6 * b + 4) * kHT];
            float4 v5 = tp[tid + (6 * b + 5) * kHT];
            bump_tgt4(h, v0); bump_tgt4(h, v1); bump_tgt4(h, v2);
            bump_tgt4(h, v3); bump_tgt4(h, v4); bump_tgt4(h, v5);
        }
    }
    __syncthreads();
    // flush packed partial: plain coalesced stores, no atomics
    int seg = z * kB + s;
    unsigned* dst = partial + ((size_t)seg * kChunks + c) * kWords;
    for (int i = tid; i < kWords; i += kHT) dst[i] = h[i];
}

// ---- match: per-sample partial-sum + scan + CDF mass matching + finish ---
// One block per sample. Thread t owns bins [16t, 16t+16): accumulates them
// from the u8-packed chunk partials (registers), participates in a dual
// block scan, writes the tgt INCLUSIVE cdf to LDS, then walks its own pred
// bins against the block-local global CDF. No windows, no global search.
__global__ __launch_bounds__(1024) void match_kernel(const unsigned* __restrict__ partial,
                                                     double* __restrict__ acc,
                                                     unsigned* __restrict__ ctr,
                                                     float* __restrict__ out) {
    int s = blockIdx.x, tid = threadIdx.x;
    int lane = tid & 63, wv = tid >> 6;                  // 16 waves
    __shared__ unsigned icdf[kNBin];                     // 64 KiB inclusive tgt CDF
    __shared__ unsigned wsp[16], wsq[16];
    __shared__ double shm[16];

    // 1. sum the 16 chunk partials; thread owns words 4t..4t+3 (one uint4)
    const uint4* bp = (const uint4*)(partial + (size_t)s        * kChunks * kWords) + tid;
    const uint4* bq = (const uint4*)(partial + (size_t)(kB + s) * kChunks * kWords) + tid;
    const unsigned M = 0x00FF00FFu;
    unsigned evp[4] = {0,0,0,0}, odp[4] = {0,0,0,0};
    unsigned evq[4] = {0,0,0,0}, odq[4] = {0,0,0,0};
#pragma unroll 4
    for (int c = 0; c < kChunks; ++c) {
        uint4 vp = bp[c * (kWords / 4)];
        uint4 vq = bq[c * (kWords / 4)];
        evp[0] += vp.x & M; odp[0] += (vp.x >> 8) & M;
        evp[1] += vp.y & M; odp[1] += (vp.y >> 8) & M;
        evp[2] += vp.z & M; odp[2] += (vp.z >> 8) & M;
        evp[3] += vp.w & M; odp[3] += (vp.w >> 8) & M;
        evq[0] += vq.x & M; odq[0] += (vq.x >> 8) & M;
        evq[1] += vq.y & M; odq[1] += (vq.y >> 8) & M;
        evq[2] += vq.z & M; odq[2] += (vq.z >> 8) & M;
        evq[3] += vq.w & M; odq[3] += (vq.w >> 8) & M;
    }
    unsigned cp[kBinsPerThr], cq[kBinsPerThr];
#pragma unroll
    for (int w = 0; w < 4; ++w) {
        cp[4*w+0] = evp[w] & 0xFFFFu; cp[4*w+1] = odp[w] & 0xFFFFu;
        cp[4*w+2] = evp[w] >> 16;     cp[4*w+3] = odp[w] >> 16;
        cq[4*w+0] = evq[w] & 0xFFFFu; cq[4*w+1] = odq[w] & 0xFFFFu;
        cq[4*w+2] = evq[w] >> 16;     cq[4*w+3] = odq[w] >> 16;
    }

    // 2. dual block-wide exclusive scan of per-thread totals
    unsigned sp = 0, sq = 0;
#pragma unroll
    for (int j = 0; j < kBinsPerThr; ++j) { sp += cp[j]; sq += cq[j]; }
    unsigned scp = sp, scq = sq;
#pragma unroll
    for (int d = 1; d < 64; d <<= 1) {
        unsigned up = __shfl_up(scp, d, 64), uq = __shfl_up(scq, d, 64);
        if (lane >= d) { scp += up; scq += uq; }
    }
    if (lane == 63) { wsp[wv] = scp; wsq[wv] = scq; }
    __syncthreads();
    if (wv == 0) {
        unsigned a = (lane < 16) ? wsp[lane] : 0u;
        unsigned b = (lane < 16) ? wsq[lane] : 0u;
        unsigned sa = a, sb = b;
#pragma unroll
        for (int d = 1; d < 16; d <<= 1) {
            unsigned ua = __shfl_up(sa, d, 64), ub = __shfl_up(sb, d, 64);
            if (lane >= d) { sa += ua; sb += ub; }
        }
        if (lane < 16) { wsp[lane] = sa - a; wsq[lane] = sb - b; }  // exclusive
    }
    __syncthreads();
    unsigned excl_p = wsp[wv] + scp - sp;                // global exclusive cdf @ bin 16t
    unsigned excl_q = wsq[wv] + scq - sq;
    // write tgt inclusive cdf
    unsigned run = excl_q;
#pragma unroll
    for (int j = 0; j < kBinsPerThr; ++j) { run += cq[j]; icdf[kBinsPerThr * tid + j] = run; }
    __syncthreads();

    // 3. walk: CDF mass matching over this thread's 16 pred bins
    double cross = 0.0;
    if (sp) {
        unsigned cur = excl_p;
        int lo = 0, hi = kNBin - 1;                      // first k: icdf[k] > cur
        while (lo < hi) { int mid = (lo + hi) >> 1; if (icdf[mid] > cur) hi = mid; else lo = mid + 1; }
        int k = lo;
#pragma unroll 1
        for (int j = 0; j < kBinsPerThr; ++j) {
            unsigned c = cp[j];
            if (!c) continue;
            unsigned endr = cur + c;
            double P = ((double)(kBinsPerThr * tid + j) + 0.5) * kWd;
            while (cur < endr) {
                unsigned e = icdf[k];
                if (e > cur) {
                    unsigned take = (e < endr ? e : endr) - cur;
                    double d = P - ((double)k + 0.5) * kWd;
                    cross += (double)take * d * d;
                    cur += take;
                }
                if (e <= cur) ++k;                       // k exhausted
            }
        }
    }

    // 4. block f64 reduce -> one atomicAdd per block; last rank writes out
    for (int o = 32; o > 0; o >>= 1) cross += __shfl_down(cross, o, 64);
    if (lane == 0) shm[wv] = cross;
    __syncthreads();
    if (tid == 0) {
        double blk = 0.0;
#pragma unroll
        for (int i = 0; i < 16; ++i) blk += shm[i];
        atomicAdd(acc, blk);
        __threadfence();                                 // release acc before ctr (16 total)
        unsigned r = atomicAdd(ctr, 1u);
        if (r == kB - 1) {
            double C = atomicAdd(acc, 0.0);              // coherent atomic read
            out[0] = (float)(C / ((double)kB * (double)kN));
        }
    }
}

extern "C" void kernel_launch(void* const* d_in, const int* in_sizes, int n_in,
                              void* d_out, int out_size, void* d_ws, size_t ws_size,
                              hipStream_t stream) {
    const float4* x = (const float4*)d_in[0];   // [16,2,768,768]
    const float4* t = (const float4*)d_in[1];   // [16,768,768]
    float* out = (float*)d_out;

    char* ws = (char*)d_ws;
    double*   acc  = (double*)  (ws + ACC_OFF);
    unsigned* ctr  = (unsigned*)(ws + CTR_OFF);
    unsigned* part = (unsigned*)(ws + PART_OFF);

    hist_kernel <<<dim3(kChunks, kB, 2), kHT,  0, stream>>>(x, t, part, acc, ctr);
    match_kernel<<<dim3(kB),             1024, 0, stream>>>(part, acc, ctr, out);
}

// Round 6
// 158.153 us; speedup vs baseline: 1.0317x; 1.0317x over previous
//
#include <hip/hip_runtime.h>
#include <math.h>

// ---------------------------------------------------------------------------
// WassersteinLoss: pred = sigmoid(x1-x0); loss = mean_b mean_i
// (sort(pred_b)[i] - sort(tgt_b)[i])^2.
//
// Histogram-based: 16384-bin value histograms per segment (bin-count halving
// validated by R15: absmax 0.0); sorted-pair matching == CDF mass matching;
// loss = Sum take*(Pc-Qc)^2 / (B*N) with bin-center values.
//
// R16: R15's fused match was strangled at 16 blocks (6% of machine, ~50us by
// boundary-calibrated budget) + stride-16 icdf LDS writes (2-bank, ~32-way
// conflict). Fix: 256-block match (16 slices x 16 samples) -- each block
// REDUNDANTLY re-sums+scans its whole sample (512KB read, L3-resident
// partials => cheap aggregate) but walks only its 1024-bin pred slice, with
// slice counts/prefixes redistributed via LDS so all 1024 threads walk 1 bin
// each. icdf padded (addr = k + (k>>4)) -> conflict-free writes. Finish via
// 256-double partial buffer + tiny fin kernel: NO device fences (R12: ~75ns/
// block serialized fence; 256 fences ~ 19us > one 11us boundary).
// Dispatches: hist + match + fin = 3.
// ---------------------------------------------------------------------------

namespace {
constexpr int kB      = 16;
constexpr int kN      = 768 * 768;        // 589824 per segment
constexpr int kNBin   = 16384;
constexpr int kChunks = 16;               // partials per segment
constexpr int kChunk  = kN / kChunks;     // 36864 elements
constexpr int kWords  = kNBin / 4;        // 4096 u32 words (4 bins/word, u8)
constexpr int kHT     = 512;              // hist block size
constexpr int kBinsPerThr = kNBin / 1024; // 16 bins per match thread
constexpr int kSlices = 16;               // match blocks per sample
constexpr int kSliceBins = kNBin / kSlices;  // 1024 pred bins per block
constexpr int kCPart  = kB * kSlices;     // 256 f64 partials
constexpr double kWd  = 1.0 / (double)kNBin;

// d_ws layout
constexpr size_t CP_OFF   = 0;                                   // double[256]
constexpr size_t PART_OFF = 65536;                               // u32[512][4096] = 8 MiB
}

__device__ __forceinline__ float pred_of(float x0, float x1) {
    // sigmoid(x1-x0), fast path: v_mul+v_exp+v_add+v_rcp (~1 ulp).
    return __builtin_amdgcn_rcpf(1.0f + __expf(x0 - x1));
}
__device__ __forceinline__ int bin_of(float v) {
    int b = (int)(v * (float)kNBin);
    return b < 0 ? 0 : (b > kNBin - 1 ? kNBin - 1 : b);
}
__device__ __forceinline__ void bump(unsigned* h, float v) {
    int b = bin_of(v);
    atomicAdd(&h[b >> 2], 1u << ((b & 3) << 3));
}
__device__ __forceinline__ void bump_pred4(unsigned* h, float4 a, float4 b) {
    bump(h, pred_of(a.x, b.x)); bump(h, pred_of(a.y, b.y));
    bump(h, pred_of(a.z, b.z)); bump(h, pred_of(a.w, b.w));
}
__device__ __forceinline__ void bump_tgt4(unsigned* h, float4 v) {
    bump(h, v.x); bump(h, v.y); bump(h, v.z); bump(h, v.w);
}
// padded LDS index: kills stride-16 bank pathology (2 banks -> all 32)
__device__ __forceinline__ int swz(int k) { return k + (k >> 4); }

// ---- histogram (LDS-private, packed u8), 512-thr blocks ------------------
__global__ __launch_bounds__(kHT) void hist_kernel(const float4* __restrict__ x,
                                                   const float4* __restrict__ t,
                                                   unsigned* __restrict__ partial) {
    int s = blockIdx.y, c = blockIdx.x, z = blockIdx.z, tid = threadIdx.x;
    __shared__ unsigned h[kWords];                       // 16 KiB, 4 bins/word
    for (int i = tid; i < kWords; i += kHT) h[i] = 0;
    __syncthreads();

    const int q4 = kN / 4, c4 = kChunk / 4;              // 9216 -> 18/thread
    if (z == 0) {
        const float4* x0p = x + (size_t)s * 2 * q4 + (size_t)c * c4;
        const float4* x1p = x0p + q4;
#pragma unroll
        for (int b = 0; b < 6; ++b) {
            int k0 = tid + (3 * b + 0) * kHT;
            int k1 = tid + (3 * b + 1) * kHT;
            int k2 = tid + (3 * b + 2) * kHT;
            // 6 independent loads in flight before first use
            float4 a0 = x0p[k0], b0 = x1p[k0];
            float4 a1 = x0p[k1], b1 = x1p[k1];
            float4 a2 = x0p[k2], b2 = x1p[k2];
            bump_pred4(h, a0, b0);
            bump_pred4(h, a1, b1);
            bump_pred4(h, a2, b2);
        }
    } else {
        const float4* tp = t + (size_t)s * q4 + (size_t)c * c4;
#pragma unroll
        for (int b = 0; b < 3; ++b) {
            float4 v0 = tp[tid + (6 * b + 0) * kHT];
            float4 v1 = tp[tid + (6 * b + 1) * kHT];
            float4 v2 = tp[tid + (6 * b + 2) * kHT];
            float4 v3 = tp[tid + (6 * b + 3) * kHT];
            float4 v4 = tp[tid + (6 * b + 4) * kHT];
            float4 v5 = tp[tid + (6 * b + 5) * kHT];
            bump_tgt4(h, v0); bump_tgt4(h, v1); bump_tgt4(h, v2);
            bump_tgt4(h, v3); bump_tgt4(h, v4); bump_tgt4(h, v5);
        }
    }
    __syncthreads();
    // flush packed partial: plain coalesced stores, no atomics
    int seg = z * kB + s;
    unsigned* dst = partial + ((size_t)seg * kChunks + c) * kWords;
    for (int i = tid; i < kWords; i += kHT) dst[i] = h[i];
}

// ---- match: per-(sample,slice) redundant reduce + scan + slice walk ------
// Block (slice, s): re-sums+scans the WHOLE sample's partials (redundant by
// 16x, L3-resident), builds full tgt inclusive CDF in padded LDS, then all
// 1024 threads walk one pred bin of the block's 1024-bin slice.
__global__ __launch_bounds__(1024) void match_kernel(const unsigned* __restrict__ partial,
                                                     double* __restrict__ cpart) {
    int slice = blockIdx.x, s = blockIdx.y, tid = threadIdx.x;
    int lane = tid & 63, wv = tid >> 6;                  // 16 waves
    __shared__ unsigned icdf[kNBin + kNBin / 16];        // padded: 68 KiB
    __shared__ unsigned s_cp[kSliceBins], s_r0[kSliceBins];
    __shared__ unsigned wsp[16], wsq[16];
    __shared__ double shm[16];

    // 1. sum the 16 chunk partials; thread owns words 4t..4t+3 (one uint4)
    const uint4* bp = (const uint4*)(partial + (size_t)s        * kChunks * kWords) + tid;
    const uint4* bq = (const uint4*)(partial + (size_t)(kB + s) * kChunks * kWords) + tid;
    const unsigned M = 0x00FF00FFu;
    unsigned evp[4] = {0,0,0,0}, odp[4] = {0,0,0,0};
    unsigned evq[4] = {0,0,0,0}, odq[4] = {0,0,0,0};
#pragma unroll 4
    for (int c = 0; c < kChunks; ++c) {
        uint4 vp = bp[c * (kWords / 4)];
        uint4 vq = bq[c * (kWords / 4)];
        evp[0] += vp.x & M; odp[0] += (vp.x >> 8) & M;
        evp[1] += vp.y & M; odp[1] += (vp.y >> 8) & M;
        evp[2] += vp.z & M; odp[2] += (vp.z >> 8) & M;
        evp[3] += vp.w & M; odp[3] += (vp.w >> 8) & M;
        evq[0] += vq.x & M; odq[0] += (vq.x >> 8) & M;
        evq[1] += vq.y & M; odq[1] += (vq.y >> 8) & M;
        evq[2] += vq.z & M; odq[2] += (vq.z >> 8) & M;
        evq[3] += vq.w & M; odq[3] += (vq.w >> 8) & M;
    }
    unsigned cp[kBinsPerThr], cq[kBinsPerThr];
#pragma unroll
    for (int w = 0; w < 4; ++w) {
        cp[4*w+0] = evp[w] & 0xFFFFu; cp[4*w+1] = odp[w] & 0xFFFFu;
        cp[4*w+2] = evp[w] >> 16;     cp[4*w+3] = odp[w] >> 16;
        cq[4*w+0] = evq[w] & 0xFFFFu; cq[4*w+1] = odq[w] & 0xFFFFu;
        cq[4*w+2] = evq[w] >> 16;     cq[4*w+3] = odq[w] >> 16;
    }

    // 2. dual block-wide exclusive scan of per-thread totals
    unsigned sp = 0, sq = 0;
#pragma unroll
    for (int j = 0; j < kBinsPerThr; ++j) { sp += cp[j]; sq += cq[j]; }
    unsigned scp = sp, scq = sq;
#pragma unroll
    for (int d = 1; d < 64; d <<= 1) {
        unsigned up = __shfl_up(scp, d, 64), uq = __shfl_up(scq, d, 64);
        if (lane >= d) { scp += up; scq += uq; }
    }
    if (lane == 63) { wsp[wv] = scp; wsq[wv] = scq; }
    __syncthreads();
    if (wv == 0) {
        unsigned a = (lane < 16) ? wsp[lane] : 0u;
        unsigned b = (lane < 16) ? wsq[lane] : 0u;
        unsigned sa = a, sb = b;
#pragma unroll
        for (int d = 1; d < 16; d <<= 1) {
            unsigned ua = __shfl_up(sa, d, 64), ub = __shfl_up(sb, d, 64);
            if (lane >= d) { sa += ua; sb += ub; }
        }
        if (lane < 16) { wsp[lane] = sa - a; wsq[lane] = sb - b; }  // exclusive
    }
    __syncthreads();
    unsigned excl_p = wsp[wv] + scp - sp;                // global excl cdf @ bin 16t
    unsigned excl_q = wsq[wv] + scq - sq;
    // write tgt inclusive cdf (padded layout: conflict-free)
    unsigned run = excl_q;
#pragma unroll
    for (int j = 0; j < kBinsPerThr; ++j) {
        run += cq[j];
        icdf[swz(kBinsPerThr * tid + j)] = run;
    }
    // redistribute this block's pred slice: wave #slice owns those bins
    if ((tid >> 6) == slice) {
        int base = (tid & 63) * kBinsPerThr;             // slice-local index
        unsigned rp = excl_p;
#pragma unroll
        for (int j = 0; j < kBinsPerThr; ++j) {
            s_cp[base + j] = cp[j];
            s_r0[base + j] = rp;
            rp += cp[j];
        }
    }
    __syncthreads();

    // 3. walk: each thread matches ONE pred bin of the slice against tgt CDF
    double cross = 0.0;
    {
        unsigned c = s_cp[tid];
        if (c) {
            unsigned cur = s_r0[tid];
            unsigned endr = cur + c;
            double P = ((double)(slice * kSliceBins + tid) + 0.5) * kWd;
            int lo = 0, hi = kNBin - 1;                  // first k: icdf[k] > cur
            while (lo < hi) {
                int mid = (lo + hi) >> 1;
                if (icdf[swz(mid)] > cur) hi = mid; else lo = mid + 1;
            }
            int k = lo;
            while (cur < endr) {
                unsigned e = icdf[swz(k)];
                if (e > cur) {
                    unsigned take = (e < endr ? e : endr) - cur;
                    double d = P - ((double)k + 0.5) * kWd;
                    cross += (double)take * d * d;
                    cur += take;
                }
                if (e <= cur) ++k;
            }
        }
    }

    // 4. block f64 reduce -> one partial slot (plain store, no fences)
    for (int o = 32; o > 0; o >>= 1) cross += __shfl_down(cross, o, 64);
    if (lane == 0) shm[wv] = cross;
    __syncthreads();
    if (tid == 0) {
        double blk = 0.0;
#pragma unroll
        for (int i = 0; i < 16; ++i) blk += shm[i];
        cpart[s * kSlices + slice] = blk;
    }
}

// ---- final reduction of 256 partial doubles ------------------------------
__global__ __launch_bounds__(256) void fin_kernel(const double* __restrict__ cpart,
                                                  float* __restrict__ out) {
    int tid = threadIdx.x, lane = tid & 63, w = tid >> 6;
    double cs = cpart[tid];
    for (int o = 32; o > 0; o >>= 1) cs += __shfl_down(cs, o, 64);
    __shared__ double shc[4];
    if (lane == 0) shc[w] = cs;
    __syncthreads();
    if (tid == 0) {
        double C = shc[0] + shc[1] + shc[2] + shc[3];
        out[0] = (float)(C / ((double)kB * (double)kN));
    }
}

extern "C" void kernel_launch(void* const* d_in, const int* in_sizes, int n_in,
                              void* d_out, int out_size, void* d_ws, size_t ws_size,
                              hipStream_t stream) {
    const float4* x = (const float4*)d_in[0];   // [16,2,768,768]
    const float4* t = (const float4*)d_in[1];   // [16,768,768]
    float* out = (float*)d_out;

    char* ws = (char*)d_ws;
    double*   cpart = (double*)  (ws + CP_OFF);
    unsigned* part  = (unsigned*)(ws + PART_OFF);

    hist_kernel <<<dim3(kChunks, kB, 2), kHT,  0, stream>>>(x, t, part);
    match_kernel<<<dim3(kSlices, kB),    1024, 0, stream>>>(part, cpart);
    fin_kernel  <<<1, 256, 0, stream>>>(cpart, out);
}

// Round 7
// 152.838 us; speedup vs baseline: 1.0676x; 1.0348x over previous
//
#include <hip/hip_runtime.h>
#include <math.h>

// ---------------------------------------------------------------------------
// WassersteinLoss: pred = sigmoid(x1-x0); loss = mean_b mean_i
// (sort(pred_b)[i] - sort(tgt_b)[i])^2.
//
// Histogram-based: 16384-bin value histograms per segment (validated R15/R16:
// absmax 0.0); sorted-pair matching == CDF mass matching; loss =
// Sum take*(Pc-Qc)^2 / (B*N) with bin-center values.
//
// R17: two-dispatch minimum. R0/R15/R16 all plateau ~157 because finish
// variants trade launch gaps (~14us each, revised calibration) against
// redundant re-reads equally. This round cuts both: (1) kSlices 16->4 (64
// match blocks): redundant partial re-read 128MB -> 32MB through L3; LDS
// 100KB/block (1 block/CU) -- kernel is BW/load-bound, not occupancy-bound.
// (2) fin eliminated: hist zeroes out[0] (strict stream order), match blocks
// f32-atomicAdd pre-divided partials (64 single-address atomics ~0.8us; f32
// rounding ~3e-7 << tol; R12's fence trap avoided -- plain atomics, no
// device-scope fence/spin). Dispatches: hist + match = 2.
// ---------------------------------------------------------------------------

namespace {
constexpr int kB      = 16;
constexpr int kN      = 768 * 768;        // 589824 per segment
constexpr int kNBin   = 16384;
constexpr int kChunks = 16;               // partials per segment
constexpr int kChunk  = kN / kChunks;     // 36864 elements
constexpr int kWords  = kNBin / 4;        // 4096 u32 words (4 bins/word, u8)
constexpr int kHT     = 512;              // hist block size
constexpr int kBinsPerThr = kNBin / 1024; // 16 bins per match thread
constexpr int kSlices = 4;                // match blocks per sample
constexpr int kSliceBins = kNBin / kSlices;        // 4096 pred bins per block
constexpr int kThrPerSlice = kSliceBins / kBinsPerThr;  // 256 owner threads
constexpr double kWd  = 1.0 / (double)kNBin;
constexpr double kInv = 1.0 / ((double)kB * (double)kN);

// d_ws layout
constexpr size_t PART_OFF = 65536;        // u32[512][4096] = 8 MiB
}

__device__ __forceinline__ float pred_of(float x0, float x1) {
    // sigmoid(x1-x0), fast path: v_mul+v_exp+v_add+v_rcp (~1 ulp).
    return __builtin_amdgcn_rcpf(1.0f + __expf(x0 - x1));
}
__device__ __forceinline__ int bin_of(float v) {
    int b = (int)(v * (float)kNBin);
    return b < 0 ? 0 : (b > kNBin - 1 ? kNBin - 1 : b);
}
__device__ __forceinline__ void bump(unsigned* h, float v) {
    int b = bin_of(v);
    atomicAdd(&h[b >> 2], 1u << ((b & 3) << 3));
}
__device__ __forceinline__ void bump_pred4(unsigned* h, float4 a, float4 b) {
    bump(h, pred_of(a.x, b.x)); bump(h, pred_of(a.y, b.y));
    bump(h, pred_of(a.z, b.z)); bump(h, pred_of(a.w, b.w));
}
__device__ __forceinline__ void bump_tgt4(unsigned* h, float4 v) {
    bump(h, v.x); bump(h, v.y); bump(h, v.z); bump(h, v.w);
}
// padded LDS index: kills stride-16 bank pathology (2 banks -> all 32)
__device__ __forceinline__ int swz(int k) { return k + (k >> 4); }

// ---- histogram (LDS-private, packed u8), 512-thr blocks ------------------
__global__ __launch_bounds__(kHT) void hist_kernel(const float4* __restrict__ x,
                                                   const float4* __restrict__ t,
                                                   unsigned* __restrict__ partial,
                                                   float* __restrict__ out) {
    int s = blockIdx.y, c = blockIdx.x, z = blockIdx.z, tid = threadIdx.x;
    if (s == 0 && c == 0 && z == 0 && tid == 0) out[0] = 0.0f;  // match accumulates
    __shared__ unsigned h[kWords];                       // 16 KiB, 4 bins/word
    for (int i = tid; i < kWords; i += kHT) h[i] = 0;
    __syncthreads();

    const int q4 = kN / 4, c4 = kChunk / 4;              // 9216 -> 18/thread
    if (z == 0) {
        const float4* x0p = x + (size_t)s * 2 * q4 + (size_t)c * c4;
        const float4* x1p = x0p + q4;
#pragma unroll
        for (int b = 0; b < 6; ++b) {
            int k0 = tid + (3 * b + 0) * kHT;
            int k1 = tid + (3 * b + 1) * kHT;
            int k2 = tid + (3 * b + 2) * kHT;
            // 6 independent loads in flight before first use
            float4 a0 = x0p[k0], b0 = x1p[k0];
            float4 a1 = x0p[k1], b1 = x1p[k1];
            float4 a2 = x0p[k2], b2 = x1p[k2];
            bump_pred4(h, a0, b0);
            bump_pred4(h, a1, b1);
            bump_pred4(h, a2, b2);
        }
    } else {
        const float4* tp = t + (size_t)s * q4 + (size_t)c * c4;
#pragma unroll
        for (int b = 0; b < 3; ++b) {
            float4 v0 = tp[tid + (6 * b + 0) * kHT];
            float4 v1 = tp[tid + (6 * b + 1) * kHT];
            float4 v2 = tp[tid + (6 * b + 2) * kHT];
            float4 v3 = tp[tid + (6 * b + 3) * kHT];
            float4 v4 = tp[tid + (6 * b + 4) * kHT];
            float4 v5 = tp[tid + (6 * b + 5) * kHT];
            bump_tgt4(h, v0); bump_tgt4(h, v1); bump_tgt4(h, v2);
            bump_tgt4(h, v3); bump_tgt4(h, v4); bump_tgt4(h, v5);
        }
    }
    __syncthreads();
    // flush packed partial: plain coalesced stores, no atomics
    int seg = z * kB + s;
    unsigned* dst = partial + ((size_t)seg * kChunks + c) * kWords;
    for (int i = tid; i < kWords; i += kHT) dst[i] = h[i];
}

// ---- match: per-(sample,slice) redundant reduce + scan + slice walk ------
// Block (slice, s): re-sums+scans the whole sample's partials (4x redundant,
// L3-resident), builds full tgt inclusive CDF in padded LDS, then all 1024
// threads walk 4 pred bins of the block's 4096-bin slice. Finishes with one
// f32 atomicAdd of the pre-divided block partial -- no fin kernel, no fences.
__global__ __launch_bounds__(1024) void match_kernel(const unsigned* __restrict__ partial,
                                                     float* __restrict__ out) {
    int slice = blockIdx.x, s = blockIdx.y, tid = threadIdx.x;
    int lane = tid & 63, wv = tid >> 6;                  // 16 waves
    __shared__ unsigned icdf[kNBin + kNBin / 16];        // padded: 68 KiB
    __shared__ unsigned s_cp[kSliceBins], s_r0[kSliceBins];  // 2 x 16 KiB
    __shared__ unsigned wsp[16], wsq[16];
    __shared__ double shm[16];

    // 1. sum the 16 chunk partials; thread owns words 4t..4t+3 (one uint4)
    const uint4* bp = (const uint4*)(partial + (size_t)s        * kChunks * kWords) + tid;
    const uint4* bq = (const uint4*)(partial + (size_t)(kB + s) * kChunks * kWords) + tid;
    const unsigned M = 0x00FF00FFu;
    unsigned evp[4] = {0,0,0,0}, odp[4] = {0,0,0,0};
    unsigned evq[4] = {0,0,0,0}, odq[4] = {0,0,0,0};
#pragma unroll 4
    for (int c = 0; c < kChunks; ++c) {
        uint4 vp = bp[c * (kWords / 4)];
        uint4 vq = bq[c * (kWords / 4)];
        evp[0] += vp.x & M; odp[0] += (vp.x >> 8) & M;
        evp[1] += vp.y & M; odp[1] += (vp.y >> 8) & M;
        evp[2] += vp.z & M; odp[2] += (vp.z >> 8) & M;
        evp[3] += vp.w & M; odp[3] += (vp.w >> 8) & M;
        evq[0] += vq.x & M; odq[0] += (vq.x >> 8) & M;
        evq[1] += vq.y & M; odq[1] += (vq.y >> 8) & M;
        evq[2] += vq.z & M; odq[2] += (vq.z >> 8) & M;
        evq[3] += vq.w & M; odq[3] += (vq.w >> 8) & M;
    }
    unsigned cp[kBinsPerThr], cq[kBinsPerThr];
#pragma unroll
    for (int w = 0; w < 4; ++w) {
        cp[4*w+0] = evp[w] & 0xFFFFu; cp[4*w+1] = odp[w] & 0xFFFFu;
        cp[4*w+2] = evp[w] >> 16;     cp[4*w+3] = odp[w] >> 16;
        cq[4*w+0] = evq[w] & 0xFFFFu; cq[4*w+1] = odq[w] & 0xFFFFu;
        cq[4*w+2] = evq[w] >> 16;     cq[4*w+3] = odq[w] >> 16;
    }

    // 2. dual block-wide exclusive scan of per-thread totals
    unsigned sp = 0, sq = 0;
#pragma unroll
    for (int j = 0; j < kBinsPerThr; ++j) { sp += cp[j]; sq += cq[j]; }
    unsigned scp = sp, scq = sq;
#pragma unroll
    for (int d = 1; d < 64; d <<= 1) {
        unsigned up = __shfl_up(scp, d, 64), uq = __shfl_up(scq, d, 64);
        if (lane >= d) { scp += up; scq += uq; }
    }
    if (lane == 63) { wsp[wv] = scp; wsq[wv] = scq; }
    __syncthreads();
    if (wv == 0) {
        unsigned a = (lane < 16) ? wsp[lane] : 0u;
        unsigned b = (lane < 16) ? wsq[lane] : 0u;
        unsigned sa = a, sb = b;
#pragma unroll
        for (int d = 1; d < 16; d <<= 1) {
            unsigned ua = __shfl_up(sa, d, 64), ub = __shfl_up(sb, d, 64);
            if (lane >= d) { sa += ua; sb += ub; }
        }
        if (lane < 16) { wsp[lane] = sa - a; wsq[lane] = sb - b; }  // exclusive
    }
    __syncthreads();
    unsigned excl_p = wsp[wv] + scp - sp;                // global excl cdf @ bin 16t
    unsigned excl_q = wsq[wv] + scq - sq;
    // write tgt inclusive cdf (padded layout: conflict-free)
    unsigned run = excl_q;
#pragma unroll
    for (int j = 0; j < kBinsPerThr; ++j) {
        run += cq[j];
        icdf[swz(kBinsPerThr * tid + j)] = run;
    }
    // redistribute this block's pred slice: owner threads [256*slice, 256*slice+256)
    if ((tid >> 8) == slice) {
        int base = (tid & (kThrPerSlice - 1)) * kBinsPerThr;   // slice-local index
        unsigned rp = excl_p;
#pragma unroll
        for (int j = 0; j < kBinsPerThr; ++j) {
            s_cp[base + j] = cp[j];
            s_r0[base + j] = rp;
            rp += cp[j];
        }
    }
    __syncthreads();

    // 3. walk: each thread matches 4 pred bins (stride-1024: conflict-free)
    double cross = 0.0;
#pragma unroll 1
    for (int j = 0; j < kSliceBins / 1024; ++j) {
        int i = tid + j * 1024;
        unsigned c = s_cp[i];
        if (!c) continue;
        unsigned cur = s_r0[i];
        unsigned endr = cur + c;
        double P = ((double)(slice * kSliceBins + i) + 0.5) * kWd;
        int lo = 0, hi = kNBin - 1;                      // first k: icdf[k] > cur
        while (lo < hi) {
            int mid = (lo + hi) >> 1;
            if (icdf[swz(mid)] > cur) hi = mid; else lo = mid + 1;
        }
        int k = lo;
        while (cur < endr) {
            unsigned e = icdf[swz(k)];
            if (e > cur) {
                unsigned take = (e < endr ? e : endr) - cur;
                double d = P - ((double)k + 0.5) * kWd;
                cross += (double)take * d * d;
                cur += take;
            }
            if (e <= cur) ++k;
        }
    }

    // 4. block f64 reduce -> one f32 atomicAdd of the pre-divided partial
    for (int o = 32; o > 0; o >>= 1) cross += __shfl_down(cross, o, 64);
    if (lane == 0) shm[wv] = cross;
    __syncthreads();
    if (tid == 0) {
        double blk = 0.0;
#pragma unroll
        for (int i = 0; i < 16; ++i) blk += shm[i];
        atomicAdd(out, (float)(blk * kInv));
    }
}

extern "C" void kernel_launch(void* const* d_in, const int* in_sizes, int n_in,
                              void* d_out, int out_size, void* d_ws, size_t ws_size,
                              hipStream_t stream) {
    const float4* x = (const float4*)d_in[0];   // [16,2,768,768]
    const float4* t = (const float4*)d_in[1];   // [16,768,768]
    float* out = (float*)d_out;

    char* ws = (char*)d_ws;
    unsigned* part = (unsigned*)(ws + PART_OFF);

    hist_kernel <<<dim3(kChunks, kB, 2), kHT,  0, stream>>>(x, t, part, out);
    match_kernel<<<dim3(kSlices, kB),    1024, 0, stream>>>(part, out);
}